// Round 2
// baseline (200.401 us; speedup 1.0000x reference)
//
#include <hip/hip_runtime.h>

#define TPB 256
#define GRID 2048

// y is exactly 0.0f or 1.0f; -(y*log(p) + (1-y)*log1p(-p)) reduces to a select.
__device__ __forceinline__ float bce1(float p, float y) {
    return (y > 0.5f) ? -__logf(p) : -__logf(1.0f - p);
}
__device__ __forceinline__ float bce4(float4 p, float4 y) {
    return bce1(p.x, y.x) + bce1(p.y, y.y) + bce1(p.z, y.z) + bce1(p.w, y.w);
}

__global__ void __launch_bounds__(TPB) hml_main(
    const float* __restrict__ l1p,
    const float* __restrict__ l2pCC,
    const float* __restrict__ l2pURW,
    const float* __restrict__ p3a, const float* __restrict__ p3b,
    const float* __restrict__ p3c, const float* __restrict__ p3d,
    const float* __restrict__ p3e,
    const float* __restrict__ l1y,
    const float* __restrict__ l2yCC,
    const float* __restrict__ l2yURW,
    const float* __restrict__ y3a, const float* __restrict__ y3b,
    const float* __restrict__ y3c, const float* __restrict__ y3d,
    const float* __restrict__ y3e,
    int nrows, double* __restrict__ acc)
{
    double s1 = 0.0, s2cc = 0.0, s2urw = 0.0, s3 = 0.0;
    double nCC = 0.0, nURW = 0.0, n3 = 0.0;

    const int tid = blockIdx.x * blockDim.x + threadIdx.x;
    const int T   = gridDim.x * blockDim.x;

    // ---------- phase A: level1 + level2 (tiny: ~0.5 iterations/thread) ----------
    for (int i = tid; i < nrows; i += T) {
        float2 p1 = ((const float2*)l1p)[i];
        float2 y1 = ((const float2*)l1y)[i];
        s1 += (double)(bce1(p1.x, y1.x) + bce1(p1.y, y1.y));

        bool aCC  = (y1.x > 0.5f);
        bool aURW = (y1.y > 0.5f);

        if (aCC) {
            nCC += 1.0;
            float s = 0.f;
            #pragma unroll
            for (int k = 0; k < 3; ++k)
                s += bce1(l2pCC[i * 3 + k], l2yCC[i * 3 + k]);
            s2cc += (double)s;
        }
        if (aURW) {
            nURW += 1.0;
            float2 p = ((const float2*)l2pURW)[i];
            float2 y = ((const float2*)l2yURW)[i];
            s2urw += (double)(bce1(p.x, y.x) + bce1(p.y, y.y));
        }
    }

    // ---------- phase B: all 5 level3 entries fused per vector index ----------
    // Per iteration: issue ALL mask-input loads in parallel (independent addrs),
    // compute 5 predicate bits, then issue up to 10 independent float4 payload
    // loads before consuming any -> ~10-way MLP instead of a serial chain.
    const long nvec = (long)nrows * 8;   // 32 floats per row = 8 float4

    const float4* P0 = (const float4*)p3a; const float4* Q0 = (const float4*)y3a;
    const float4* P1 = (const float4*)p3b; const float4* Q1 = (const float4*)y3b;
    const float4* P2 = (const float4*)p3c; const float4* Q2 = (const float4*)y3c;
    const float4* P3v= (const float4*)p3d; const float4* Q3 = (const float4*)y3d;
    const float4* P4 = (const float4*)p3e; const float4* Q4 = (const float4*)y3e;

    for (long v = tid; v < nvec; v += T) {
        const int row = (int)(v >> 3);

        // independent mask-input loads (all issued before any use)
        float2 y1 = ((const float2*)l1y)[row];
        float  c0 = l2yCC[row * 3 + 0];
        float  c1 = l2yCC[row * 3 + 1];
        float  c2 = l2yCC[row * 3 + 2];
        float2 u  = ((const float2*)l2yURW)[row];

        const bool aCC  = (y1.x > 0.5f);
        const bool aURW = (y1.y > 0.5f);
        const bool m0 = aCC  && (c0  != 0.0f);
        const bool m1 = aCC  && (c1  != 0.0f);
        const bool m2 = aCC  && (c2  != 0.0f);
        const bool m3 = aURW && (u.x != 0.0f);
        const bool m4 = aURW && (u.y != 0.0f);

        // issue payload loads for all active entries (independent, overlap)
        float4 pa, pb, pc, pd, pe, qa, qb, qc, qd, qe;
        if (m0) { pa = P0[v];  qa = Q0[v]; }
        if (m1) { pb = P1[v];  qb = Q1[v]; }
        if (m2) { pc = P2[v];  qc = Q2[v]; }
        if (m3) { pd = P3v[v]; qd = Q3[v]; }
        if (m4) { pe = P4[v];  qe = Q4[v]; }

        float s = 0.0f;
        if (m0) s += bce4(pa, qa);
        if (m1) s += bce4(pb, qb);
        if (m2) s += bce4(pc, qc);
        if (m3) s += bce4(pd, qd);
        if (m4) s += bce4(pe, qe);
        s3 += (double)s;

        if ((v & 7) == 0)
            n3 += (double)((int)m0 + (int)m1 + (int)m2 + (int)m3 + (int)m4);
    }

    // ---------- block reduction: 7 doubles ----------
    double vals[7] = { s1, s2cc, s2urw, s3, nCC, nURW, n3 };
    __shared__ double sm[4][7];
    const int lane = threadIdx.x & 63;
    const int wid  = threadIdx.x >> 6;

    #pragma unroll
    for (int j = 0; j < 7; ++j) {
        double x = vals[j];
        #pragma unroll
        for (int o = 32; o > 0; o >>= 1)
            x += __shfl_down(x, o, 64);
        if (lane == 0) sm[wid][j] = x;
    }
    __syncthreads();

    if (threadIdx.x == 0) {
        #pragma unroll
        for (int j = 0; j < 7; ++j) {
            double x = sm[0][j] + sm[1][j] + sm[2][j] + sm[3][j];
            atomicAdd(&acc[j], x);
        }
    }
}

__global__ void hml_final(const double* __restrict__ acc, float* __restrict__ out, int nrows)
{
    double s1 = acc[0], s2cc = acc[1], s2urw = acc[2], s3 = acc[3];
    double nCC = acc[4], nURW = acc[5], n3 = acc[6];

    double level1 = s1 / ((double)nrows * 2.0);

    double l2 = 0.0;
    if (nCC  > 0.0) l2 += s2cc  / (nCC  * 3.0);
    if (nURW > 0.0) l2 += s2urw / (nURW * 2.0);
    double level2 = 0.5 * l2;

    double level3 = (n3 > 0.0) ? (s3 / 32.0) / n3 : 0.0;

    out[0] = (float)(level1 + level2 + level3);
}

extern "C" void kernel_launch(void* const* d_in, const int* in_sizes, int n_in,
                              void* d_out, int out_size, void* d_ws, size_t ws_size,
                              hipStream_t stream) {
    const float* l1p   = (const float*)d_in[0];
    const float* l2pCC = (const float*)d_in[1];
    const float* l2pURW= (const float*)d_in[2];
    const float* p3a   = (const float*)d_in[3];
    const float* p3b   = (const float*)d_in[4];
    const float* p3c   = (const float*)d_in[5];
    const float* p3d   = (const float*)d_in[6];
    const float* p3e   = (const float*)d_in[7];
    const float* l1y   = (const float*)d_in[8];
    const float* l2yCC = (const float*)d_in[9];
    const float* l2yURW= (const float*)d_in[10];
    const float* y3a   = (const float*)d_in[11];
    const float* y3b   = (const float*)d_in[12];
    const float* y3c   = (const float*)d_in[13];
    const float* y3d   = (const float*)d_in[14];
    const float* y3e   = (const float*)d_in[15];

    const int nrows = in_sizes[0] / 2;

    double* acc = (double*)d_ws;
    hipMemsetAsync(acc, 0, 7 * sizeof(double), stream);

    hml_main<<<GRID, TPB, 0, stream>>>(
        l1p, l2pCC, l2pURW, p3a, p3b, p3c, p3d, p3e,
        l1y, l2yCC, l2yURW, y3a, y3b, y3c, y3d, y3e,
        nrows, acc);

    hml_final<<<1, 1, 0, stream>>>(acc, (float*)d_out, nrows);
}

// Round 3
// 163.693 us; speedup vs baseline: 1.2243x; 1.2243x over previous
//
#include <hip/hip_runtime.h>

#define TPB   256
#define GRID1 1024
#define GRID2 2048

// y is exactly 0.0f or 1.0f; -(y*log(p) + (1-y)*log1p(-p)) reduces to a select.
__device__ __forceinline__ float bce1(float p, float y) {
    return (y > 0.5f) ? -__logf(p) : -__logf(1.0f - p);
}
__device__ __forceinline__ float bce4(float4 p, float4 y) {
    return bce1(p.x, y.x) + bce1(p.y, y.y) + bce1(p.z, y.z) + bce1(p.w, y.w);
}

template<int N>
__device__ __forceinline__ void block_reduce_atomic(const double* vals, double* acc) {
    __shared__ double sm[4][N];
    const int lane = threadIdx.x & 63;
    const int wid  = threadIdx.x >> 6;
    #pragma unroll
    for (int j = 0; j < N; ++j) {
        double v = vals[j];
        #pragma unroll
        for (int o = 32; o > 0; o >>= 1)
            v += __shfl_down(v, o, 64);
        if (lane == 0) sm[wid][j] = v;
    }
    __syncthreads();
    if (threadIdx.x == 0) {
        #pragma unroll
        for (int j = 0; j < N; ++j)
            atomicAdd(&acc[j], sm[0][j] + sm[1][j] + sm[2][j] + sm[3][j]);
    }
}

// ---- kernel 1: level1 + level2 sums, per-row 5-bit activity mask, n3 count ----
__global__ void __launch_bounds__(TPB) hml_l1l2(
    const float* __restrict__ l1p, const float* __restrict__ l2pCC,
    const float* __restrict__ l2pURW, const float* __restrict__ l1y,
    const float* __restrict__ l2yCC, const float* __restrict__ l2yURW,
    int nrows, double* __restrict__ acc, unsigned char* __restrict__ mask)
{
    double s1 = 0, s2cc = 0, s2urw = 0, nCC = 0, nURW = 0, n3 = 0;
    const int tid = blockIdx.x * blockDim.x + threadIdx.x;
    const int T   = gridDim.x * blockDim.x;

    for (int i = tid; i < nrows; i += T) {
        float2 p1 = ((const float2*)l1p)[i];
        float2 y1 = ((const float2*)l1y)[i];
        float2 pu = ((const float2*)l2pURW)[i];
        float2 yu = ((const float2*)l2yURW)[i];
        float c0p = l2pCC[i*3+0], c1p = l2pCC[i*3+1], c2p = l2pCC[i*3+2];
        float c0y = l2yCC[i*3+0], c1y = l2yCC[i*3+1], c2y = l2yCC[i*3+2];

        s1 += (double)(bce1(p1.x, y1.x) + bce1(p1.y, y1.y));

        const bool aCC  = (y1.x > 0.5f);
        const bool aURW = (y1.y > 0.5f);
        const float fCC  = aCC  ? 1.f : 0.f;
        const float fURW = aURW ? 1.f : 0.f;

        // unconditional compute, mask as multiplier (no divergence)
        s2cc  += (double)(fCC  * (bce1(c0p, c0y) + bce1(c1p, c1y) + bce1(c2p, c2y)));
        s2urw += (double)(fURW * (bce1(pu.x, yu.x) + bce1(pu.y, yu.y)));
        nCC  += (double)fCC;
        nURW += (double)fURW;

        const unsigned b0 = (aCC  && c0y  != 0.f) ? 1u : 0u;
        const unsigned b1 = (aCC  && c1y  != 0.f) ? 1u : 0u;
        const unsigned b2 = (aCC  && c2y  != 0.f) ? 1u : 0u;
        const unsigned b3 = (aURW && yu.x != 0.f) ? 1u : 0u;
        const unsigned b4 = (aURW && yu.y != 0.f) ? 1u : 0u;
        n3 += (double)(b0 + b1 + b2 + b3 + b4);
        if (mask)
            mask[i] = (unsigned char)(b0 | (b1 << 1) | (b2 << 2) | (b3 << 3) | (b4 << 4));
    }

    double vals[6] = { s1, s2cc, s2urw, nCC, nURW, n3 };
    block_reduce_atomic<6>(vals, acc);
}

// ---- kernel 2: level3 — pure unconditional streaming, mask as multiplier ----
__global__ void __launch_bounds__(TPB) hml_l3(
    const float* __restrict__ p3a, const float* __restrict__ p3b,
    const float* __restrict__ p3c, const float* __restrict__ p3d,
    const float* __restrict__ p3e,
    const float* __restrict__ y3a, const float* __restrict__ y3b,
    const float* __restrict__ y3c, const float* __restrict__ y3d,
    const float* __restrict__ y3e,
    const unsigned char* __restrict__ mask,
    const float* __restrict__ l1y, const float* __restrict__ l2yCC,
    const float* __restrict__ l2yURW,
    int nrows, double* __restrict__ acc)
{
    double s3 = 0;
    const int tid = blockIdx.x * blockDim.x + threadIdx.x;
    const int T   = gridDim.x * blockDim.x;
    const int nvec = nrows * 8;   // 32 floats per row = 8 float4

    const float4* P[5] = { (const float4*)p3a, (const float4*)p3b, (const float4*)p3c,
                           (const float4*)p3d, (const float4*)p3e };
    const float4* Q[5] = { (const float4*)y3a, (const float4*)y3b, (const float4*)y3c,
                           (const float4*)y3d, (const float4*)y3e };

    #pragma unroll
    for (int e = 0; e < 5; ++e) {
        const float4* p4 = P[e];
        const float4* q4 = Q[e];
        for (int v = tid; v < nvec; v += T) {
            const int row = v >> 3;
            float mf;
            if (mask) {
                // 1-byte load, independent of the payload loads (no chain);
                // a wave's 64 lanes touch 8 consecutive bytes -> one line.
                mf = (float)((mask[row] >> e) & 1);
            } else {
                // fallback when ws too small: inline mask (still independent)
                float a = l1y[row * 2 + (e >= 3 ? 1 : 0)];
                float c = (e < 3) ? l2yCC[row * 3 + e] : l2yURW[row * 2 + (e - 3)];
                mf = (a > 0.5f && c != 0.f) ? 1.f : 0.f;
            }
            float4 p = p4[v];
            float4 q = q4[v];
            s3 += (double)(mf * bce4(p, q));
        }
    }

    double vals[1] = { s3 };
    block_reduce_atomic<1>(vals, acc + 6);
}

__global__ void hml_final(const double* __restrict__ acc, float* __restrict__ out, int nrows)
{
    double s1 = acc[0], s2cc = acc[1], s2urw = acc[2];
    double nCC = acc[3], nURW = acc[4], n3 = acc[5], s3 = acc[6];

    double level1 = s1 / ((double)nrows * 2.0);

    double l2 = 0.0;
    if (nCC  > 0.0) l2 += s2cc  / (nCC  * 3.0);
    if (nURW > 0.0) l2 += s2urw / (nURW * 2.0);
    double level2 = 0.5 * l2;

    double level3 = (n3 > 0.0) ? (s3 / 32.0) / n3 : 0.0;

    out[0] = (float)(level1 + level2 + level3);
}

extern "C" void kernel_launch(void* const* d_in, const int* in_sizes, int n_in,
                              void* d_out, int out_size, void* d_ws, size_t ws_size,
                              hipStream_t stream) {
    const float* l1p   = (const float*)d_in[0];
    const float* l2pCC = (const float*)d_in[1];
    const float* l2pURW= (const float*)d_in[2];
    const float* p3a   = (const float*)d_in[3];
    const float* p3b   = (const float*)d_in[4];
    const float* p3c   = (const float*)d_in[5];
    const float* p3d   = (const float*)d_in[6];
    const float* p3e   = (const float*)d_in[7];
    const float* l1y   = (const float*)d_in[8];
    const float* l2yCC = (const float*)d_in[9];
    const float* l2yURW= (const float*)d_in[10];
    const float* y3a   = (const float*)d_in[11];
    const float* y3b   = (const float*)d_in[12];
    const float* y3c   = (const float*)d_in[13];
    const float* y3d   = (const float*)d_in[14];
    const float* y3e   = (const float*)d_in[15];

    const int nrows = in_sizes[0] / 2;

    double* acc = (double*)d_ws;
    unsigned char* mask =
        (ws_size >= 256 + (size_t)nrows) ? ((unsigned char*)d_ws + 256) : nullptr;

    hipMemsetAsync(acc, 0, 7 * sizeof(double), stream);

    hml_l1l2<<<GRID1, TPB, 0, stream>>>(
        l1p, l2pCC, l2pURW, l1y, l2yCC, l2yURW, nrows, acc, mask);

    hml_l3<<<GRID2, TPB, 0, stream>>>(
        p3a, p3b, p3c, p3d, p3e, y3a, y3b, y3c, y3d, y3e,
        mask, l1y, l2yCC, l2yURW, nrows, acc);

    hml_final<<<1, 1, 0, stream>>>(acc, (float*)d_out, nrows);
}